// Round 3
// baseline (356.143 us; speedup 1.0000x reference)
//
#include <hip/hip_runtime.h>
#include <hip/hip_bf16.h>

#define BB   64
#define NTOT 800000
#define NF4  200000          // NTOT / 4
#define NP   128
#define NH1  256
#define NH2  128
#define NC   32
#define EPSV 1e-5f
#define BG   8               // batches per block (batch split 8-ways)

typedef float fx4 __attribute__((ext_vector_type(4)));

__device__ __forceinline__ int bitrev3(int l) {
    return ((l & 1) << 2) | (l & 2) | ((l & 4) >> 2);
}

template <int C, int M>
__device__ __forceinline__ void red_step(float* v, int lane) {
    const bool hi = (lane & M) != 0;
    #pragma unroll
    for (int j = 0; j < C / 2; ++j) {
        float mine  = hi ? v[j + C / 2] : v[j];
        float other = hi ? v[j]         : v[j + C / 2];
        v[j] = mine + __shfl_xor(other, M);
    }
}

// ---------------------------------------------------------------------------
// Scatter-reduce: WX[b, idx[n]] += x[b,n] * w[n]     (idx sorted)
// 8 loads forced simultaneously live via one asm pin -> all 8 global_load
// issued before any use. 17-shuffle-equivalent transpose-reduce -> one
// end-of-wave atomic instruction (lanes 0..7).
// ---------------------------------------------------------------------------
__global__ __launch_bounds__(256) void k_scatter(
    const float* __restrict__ x, const float* __restrict__ w,
    const int* __restrict__ idx, float* __restrict__ WX)
{
    const int n4 = blockIdx.x * 256 + threadIdx.x;   // float4 index
    if (n4 >= NF4) return;                           // whole waves only
    const int b0   = blockIdx.y * BG;
    const int lane = threadIdx.x & 63;

    const fx4  wv = reinterpret_cast<const fx4*>(w)[n4];
    const int4 pv = reinterpret_cast<const int4*>(idx)[n4];

    const bool uni_t = (pv.x == pv.w);               // sorted -> all 4 equal
    const int  fp    = __builtin_amdgcn_readfirstlane(pv.x);
    const bool wave_uni =
        (__ballot((uni_t && (pv.x == fp)) ? 1 : 0) == ~0ull);

    const fx4* __restrict__ xv =
        reinterpret_cast<const fx4*>(x) + (size_t)b0 * NF4 + n4;

    if (wave_uni) {
        fx4 x0 = xv[0];
        fx4 x1 = xv[(size_t)1 * NF4];
        fx4 x2 = xv[(size_t)2 * NF4];
        fx4 x3 = xv[(size_t)3 * NF4];
        fx4 x4 = xv[(size_t)4 * NF4];
        fx4 x5 = xv[(size_t)5 * NF4];
        fx4 x6 = xv[(size_t)6 * NF4];
        fx4 x7 = xv[(size_t)7 * NF4];
        // Pin all 8 float4 live at once: forces 8 loads in flight.
        asm volatile("" : "+v"(x0), "+v"(x1), "+v"(x2), "+v"(x3),
                          "+v"(x4), "+v"(x5), "+v"(x6), "+v"(x7));
        float v[BG];
        v[0] = fmaf(x0[0], wv[0], fmaf(x0[1], wv[1], fmaf(x0[2], wv[2], x0[3] * wv[3])));
        v[1] = fmaf(x1[0], wv[0], fmaf(x1[1], wv[1], fmaf(x1[2], wv[2], x1[3] * wv[3])));
        v[2] = fmaf(x2[0], wv[0], fmaf(x2[1], wv[1], fmaf(x2[2], wv[2], x2[3] * wv[3])));
        v[3] = fmaf(x3[0], wv[0], fmaf(x3[1], wv[1], fmaf(x3[2], wv[2], x3[3] * wv[3])));
        v[4] = fmaf(x4[0], wv[0], fmaf(x4[1], wv[1], fmaf(x4[2], wv[2], x4[3] * wv[3])));
        v[5] = fmaf(x5[0], wv[0], fmaf(x5[1], wv[1], fmaf(x5[2], wv[2], x5[3] * wv[3])));
        v[6] = fmaf(x6[0], wv[0], fmaf(x6[1], wv[1], fmaf(x6[2], wv[2], x6[3] * wv[3])));
        v[7] = fmaf(x7[0], wv[0], fmaf(x7[1], wv[1], fmaf(x7[2], wv[2], x7[3] * wv[3])));
        red_step<8, 1>(v, lane);
        red_step<4, 2>(v, lane);
        red_step<2, 4>(v, lane);
        float t = v[0];
        t += __shfl_xor(t, 8);
        t += __shfl_xor(t, 16);
        t += __shfl_xor(t, 32);
        if (lane < 8)
            atomicAdd(&WX[(b0 + bitrev3(lane)) * NP + fp], t);
    } else {  // pathway boundary inside wave (~4% of waves)
        #pragma unroll
        for (int i = 0; i < BG; ++i) {
            fx4 xr = xv[(size_t)i * NF4];
            float* row = &WX[(b0 + i) * NP];
            if (uni_t) {
                atomicAdd(&row[pv.x],
                    fmaf(xr[0], wv[0], fmaf(xr[1], wv[1], fmaf(xr[2], wv[2], xr[3] * wv[3]))));
            } else {
                atomicAdd(&row[pv.x], xr[0] * wv[0]);
                atomicAdd(&row[pv.y], xr[1] * wv[1]);
                atomicAdd(&row[pv.z], xr[2] * wv[2]);
                atomicAdd(&row[pv.w], xr[3] * wv[3]);
            }
        }
    }
}

// ---------------------------------------------------------------------------
// Fused head: BN0+gate -> fc1+ReLU+BN -> fc2+ReLU+BN -> logits+softmax.
// ONE block, 1024 threads (16 waves). All BN stats via 64-lane shuffles
// (lane == batch). LDS layouts transposed [feature][batch] so every LDS
// access is lane-consecutive (2-way, free) or broadcast. h1 goes through
// global ws transposed (64KB, L2-hot).
// ---------------------------------------------------------------------------
__device__ __forceinline__ float bn_shfl(float a, float gj, float bj) {
    // a: this lane's (batch) post-ReLU value for one column
    float s = a, q = a * a;
    #pragma unroll
    for (int off = 32; off > 0; off >>= 1) {
        s += __shfl_xor(s, off);
        q += __shfl_xor(q, off);
    }
    const float m   = s * (1.f / BB);
    const float var = q * (1.f / BB) - m * m;
    return (a - m) * rsqrtf(var + EPSV) * gj + bj;
}

__global__ __launch_bounds__(1024) void k_head_fused(
    const float* __restrict__ WX,  const float* __restrict__ co_w,
    const float* __restrict__ bn0g, const float* __restrict__ bn0b,
    const float* __restrict__ W1,  const float* __restrict__ b1,
    const float* __restrict__ bn1g, const float* __restrict__ bn1b,
    const float* __restrict__ W2,  const float* __restrict__ b2,
    const float* __restrict__ bn2g, const float* __restrict__ bn2b,
    const float* __restrict__ Wo,  const float* __restrict__ bo,
    float* __restrict__ y, float* __restrict__ Zout, float* __restrict__ h1t)
{
    __shared__ float Zt[NP * BB];    // [p][b]  32KB
    __shared__ float H2t[NH2 * BB];  // [j][b]  32KB

    const int tid  = threadIdx.x;
    const int wv   = tid >> 6;       // 0..15
    const int lane = tid & 63;       // == batch b

    // ---- stage 0: ReLU + BN0 + CancelOut gate ----
    #pragma unroll
    for (int p = wv; p < NP; p += 16) {
        float r = fmaxf(WX[lane * NP + p], 0.f);
        float s = r, q = r * r;
        #pragma unroll
        for (int off = 32; off > 0; off >>= 1) {
            s += __shfl_xor(s, off);
            q += __shfl_xor(q, off);
        }
        const float m   = s * (1.f / BB);
        const float var = q * (1.f / BB) - m * m;
        const float sig = 1.f / (1.f + expf(-co_w[p]));
        const float z   = ((r - m) * rsqrtf(var + EPSV) * bn0g[p] + bn0b[p]) * sig;
        Zt[p * BB + lane]   = z;
        Zout[lane * NP + p] = z;
    }
    __syncthreads();

    // ---- stage 1: fc1 (Z @ W1 + b1) -> ReLU -> BN -> h1t[j][b] (global) ----
    #pragma unroll
    for (int g = 0; g < 4; ++g) {
        const int j0 = wv * 16 + g * 4;
        float a0 = b1[j0], a1 = b1[j0+1], a2 = b1[j0+2], a3 = b1[j0+3];
        for (int k = 0; k < NP; ++k) {
            const float zk = Zt[k * BB + lane];
            const fx4 wr = *reinterpret_cast<const fx4*>(&W1[k * NH1 + j0]);
            a0 = fmaf(zk, wr[0], a0);
            a1 = fmaf(zk, wr[1], a1);
            a2 = fmaf(zk, wr[2], a2);
            a3 = fmaf(zk, wr[3], a3);
        }
        h1t[(j0    ) * BB + lane] = bn_shfl(fmaxf(a0, 0.f), bn1g[j0  ], bn1b[j0  ]);
        h1t[(j0 + 1) * BB + lane] = bn_shfl(fmaxf(a1, 0.f), bn1g[j0+1], bn1b[j0+1]);
        h1t[(j0 + 2) * BB + lane] = bn_shfl(fmaxf(a2, 0.f), bn1g[j0+2], bn1b[j0+2]);
        h1t[(j0 + 3) * BB + lane] = bn_shfl(fmaxf(a3, 0.f), bn1g[j0+3], bn1b[j0+3]);
    }
    __syncthreads();

    // ---- stage 2: fc2 (h1 @ W2 + b2) -> ReLU -> BN -> H2t[j][b] (LDS) ----
    #pragma unroll
    for (int g = 0; g < 2; ++g) {
        const int j0 = wv * 8 + g * 4;
        float a0 = b2[j0], a1 = b2[j0+1], a2 = b2[j0+2], a3 = b2[j0+3];
        for (int k = 0; k < NH1; ++k) {
            const float hk = h1t[k * BB + lane];
            const fx4 wr = *reinterpret_cast<const fx4*>(&W2[k * NH2 + j0]);
            a0 = fmaf(hk, wr[0], a0);
            a1 = fmaf(hk, wr[1], a1);
            a2 = fmaf(hk, wr[2], a2);
            a3 = fmaf(hk, wr[3], a3);
        }
        H2t[(j0    ) * BB + lane] = bn_shfl(fmaxf(a0, 0.f), bn2g[j0  ], bn2b[j0  ]);
        H2t[(j0 + 1) * BB + lane] = bn_shfl(fmaxf(a1, 0.f), bn2g[j0+1], bn2b[j0+1]);
        H2t[(j0 + 2) * BB + lane] = bn_shfl(fmaxf(a2, 0.f), bn2g[j0+2], bn2b[j0+2]);
        H2t[(j0 + 3) * BB + lane] = bn_shfl(fmaxf(a3, 0.f), bn2g[j0+3], bn2b[j0+3]);
    }
    __syncthreads();

    // ---- stage 3: logits + softmax. One wave per batch row. ----
    #pragma unroll
    for (int it = 0; it < 4; ++it) {
        const int b  = it * 16 + wv;
        const int c  = lane & 31;
        const int kh = lane >> 5;      // k-half: lanes 0-31 do k<64, 32-63 do k>=64
        float acc = 0.f;
        for (int k = kh * 64; k < kh * 64 + 64; ++k)
            acc = fmaf(H2t[k * BB + b], Wo[k * NC + c], acc);
        acc += __shfl_xor(acc, 32);    // combine halves: both now hold full dot
        acc += bo[c];
        float mx = acc;
        #pragma unroll
        for (int off = 16; off > 0; off >>= 1)
            mx = fmaxf(mx, __shfl_xor(mx, off));
        const float e = expf(acc - mx);
        float sm = e;
        #pragma unroll
        for (int off = 16; off > 0; off >>= 1)
            sm += __shfl_xor(sm, off);
        if (lane < 32)
            y[b * NC + c] = e / sm;
    }
}

// ---------------------------------------------------------------------------
extern "C" void kernel_launch(void* const* d_in, const int* in_sizes, int n_in,
                              void* d_out, int out_size, void* d_ws, size_t ws_size,
                              hipStream_t stream)
{
    const float* x    = (const float*)d_in[0];
    const float* w    = (const float*)d_in[1];
    const float* co_w = (const float*)d_in[2];
    const float* bn0g = (const float*)d_in[3];
    const float* bn0b = (const float*)d_in[4];
    const float* W1   = (const float*)d_in[5];
    const float* b1   = (const float*)d_in[6];
    const float* bn1g = (const float*)d_in[7];
    const float* bn1b = (const float*)d_in[8];
    const float* W2   = (const float*)d_in[9];
    const float* b2   = (const float*)d_in[10];
    const float* bn2g = (const float*)d_in[11];
    const float* bn2b = (const float*)d_in[12];
    const float* Wo   = (const float*)d_in[13];
    const float* bo   = (const float*)d_in[14];
    const int*   idx  = (const int*)d_in[15];

    float* out = (float*)d_out;
    float* y   = out;               // [64, 32]  (output 0)
    float* Z   = out + BB * NC;     // [64, 128] (output 1)

    float* WX  = (float*)d_ws;      // 8192 f32
    float* h1t = WX + BB * NP;      // 16384 f32 (h1 transposed [j][b])

    hipMemsetAsync(WX, 0, BB * NP * sizeof(float), stream);
    dim3 sgrid((NF4 + 255) / 256, BB / BG);
    k_scatter<<<sgrid, 256, 0, stream>>>(x, w, idx, WX);
    k_head_fused<<<1, 1024, 0, stream>>>(WX, co_w, bn0g, bn0b,
                                         W1, b1, bn1g, bn1b,
                                         W2, b2, bn2g, bn2b,
                                         Wo, bo, y, Z, h1t);
}